// Round 14
// baseline (249.117 us; speedup 1.0000x reference)
//
#include <hip/hip_runtime.h>

#define DIN 128
#define DOUT 128
#define EPB 4096            // edges per block for fused count
#define EPB_P 2048          // edges per block for partition (more spread)
#define BKT 512             // nodes per bucket (dst >> 9)
#define PACK_BITS 19        // src_global bits; dst_low in bits 19..27
#define SRCG_MASK ((1u << PACK_BITS) - 1u)

typedef __attribute__((ext_vector_type(8))) short short8;
typedef __attribute__((ext_vector_type(4))) float f32x4;
typedef __attribute__((ext_vector_type(8))) unsigned short ushort8;

__device__ __forceinline__ unsigned short f2bf(float f) {
  unsigned int u = __float_as_uint(f);
  u += 0x7fffu + ((u >> 16) & 1u);   // round-to-nearest-even
  return (unsigned short)(u >> 16);
}

// ============ W -> W^T bf16 (blocks 0..S-1) + zero count buffers (block S) ============

__global__ __launch_bounds__(256) void wconvert(const float* __restrict__ W,
                                                unsigned short* __restrict__ wT,
                                                int* __restrict__ zbuf, int n_sup) {
  const int tid = threadIdx.x;
  if (blockIdx.x >= n_sup) {        // zero bucket_cnt + cursor0 (512 ints)
    zbuf[tid] = 0;
    zbuf[tid + 256] = 0;
    return;
  }
  __shared__ unsigned short buf[128][136];
  const int s = blockIdx.x;
  const float* Ws = W + (size_t)s * DIN * DOUT;
  unsigned short* wts = wT + (size_t)s * DIN * DOUT;
#pragma unroll
  for (int i = 0; i < 16; ++i) {
    int e = tid + i * 256;
    int k = e >> 5, c = (e & 31) * 4;
    float4 v = *reinterpret_cast<const float4*>(&Ws[(size_t)k * DOUT + c]);
    buf[c][k] = f2bf(v.x); buf[c + 1][k] = f2bf(v.y);
    buf[c + 2][k] = f2bf(v.z); buf[c + 3][k] = f2bf(v.w);
  }
  __syncthreads();
#pragma unroll
  for (int i = 0; i < 8; ++i) {
    int e = tid + i * 256;
    int r = e >> 4, c = (e & 15) * 8;
    *reinterpret_cast<ushort8*>(&wts[(size_t)r * DIN + c]) =
        *reinterpret_cast<const ushort8*>(&buf[r][c]);
  }
}

// ======================= fused MFMA GEMM + bucket_count (r13, best) =======================

__global__ __launch_bounds__(256) void gemm_mfma_count(const float* __restrict__ x,
                                                       const unsigned short* __restrict__ wT,
                                                       unsigned short* __restrict__ pre,
                                                       const int* __restrict__ dst_all,
                                                       int* __restrict__ bucket_cnt,
                                                       int n_nodes, int n_sup, int TE,
                                                       int gemm_blocks) {
  __shared__ unsigned short cst[128][136];

  const int tid = threadIdx.x;

  if (blockIdx.x >= gemm_blocks) {
    int* cnt = reinterpret_cast<int*>(&cst[0][0]);
    cnt[tid] = 0;
    __syncthreads();
    const int cb = blockIdx.x - gemm_blocks;
    const int beg = cb * EPB;
    const int end = min(beg + EPB, TE);
    for (int i = beg + tid; i < end; i += 256) atomicAdd(&cnt[dst_all[i] >> 9], 1);
    __syncthreads();
    int c = cnt[tid];
    if (c) atomicAdd(&bucket_cnt[tid], c);
    return;
  }

  const int lane = tid & 63;
  const int w = tid >> 6;
  const int row0 = blockIdx.x * 128;
  const int alr = lane & 15;
  const int akg = lane >> 4;

  short8 xfrag[4][2];
#pragma unroll
  for (int kc = 0; kc < 4; ++kc)
#pragma unroll
    for (int mt = 0; mt < 2; ++mt) {
      int gr = row0 + w * 32 + mt * 16 + alr;
      short8 a = {0, 0, 0, 0, 0, 0, 0, 0};
      if (gr < n_nodes) {
        const float4* p =
            reinterpret_cast<const float4*>(&x[(size_t)gr * DIN + kc * 32 + akg * 8]);
        float4 v0 = p[0];
        float4 v1 = p[1];
        a[0] = (short)f2bf(v0.x); a[1] = (short)f2bf(v0.y);
        a[2] = (short)f2bf(v0.z); a[3] = (short)f2bf(v0.w);
        a[4] = (short)f2bf(v1.x); a[5] = (short)f2bf(v1.y);
        a[6] = (short)f2bf(v1.z); a[7] = (short)f2bf(v1.w);
      }
      xfrag[kc][mt] = a;
    }

  for (int s = 0; s < n_sup; ++s) {
    const unsigned short* wts = wT + (size_t)s * DIN * DOUT;

    f32x4 acc[2][8];
#pragma unroll
    for (int mt = 0; mt < 2; ++mt)
#pragma unroll
      for (int nt = 0; nt < 8; ++nt) acc[mt][nt] = (f32x4){0.f, 0.f, 0.f, 0.f};

#pragma unroll
    for (int kc = 0; kc < 4; ++kc) {
      short8 wfrag[8];
#pragma unroll
      for (int nt = 0; nt < 8; ++nt)
        wfrag[nt] = *reinterpret_cast<const short8*>(
            &wts[(size_t)(nt * 16 + alr) * DIN + kc * 32 + akg * 8]);
#pragma unroll
      for (int mt = 0; mt < 2; ++mt)
#pragma unroll
        for (int nt = 0; nt < 8; ++nt)
          acc[mt][nt] = __builtin_amdgcn_mfma_f32_16x16x32_bf16(
              wfrag[nt], xfrag[kc][mt], acc[mt][nt], 0, 0, 0);
    }

    // swapped-D: lane holds node = mt*16+alr, out-cols nt*16 + akg*4..+3
#pragma unroll
    for (int mt = 0; mt < 2; ++mt)
#pragma unroll
      for (int nt = 0; nt < 8; ++nt) {
        unsigned u0 = (unsigned)f2bf(acc[mt][nt][0]) |
                      ((unsigned)f2bf(acc[mt][nt][1]) << 16);
        unsigned u1 = (unsigned)f2bf(acc[mt][nt][2]) |
                      ((unsigned)f2bf(acc[mt][nt][3]) << 16);
        *reinterpret_cast<uint2*>(&cst[w * 32 + mt * 16 + alr][nt * 16 + akg * 4]) =
            make_uint2(u0, u1);
      }
    // no __syncthreads: wave-private rows, wave-local store below

    unsigned short* ps = pre + (size_t)s * n_nodes * DOUT;
#pragma unroll
    for (int i = 0; i < 8; ++i) {
      int e = lane + i * 64;
      int r = w * 32 + (e >> 4);
      int c = (e & 15) * 8;
      int gr = row0 + r;
      if (gr < n_nodes)
        *reinterpret_cast<ushort8*>(&ps[(size_t)gr * DOUT + c]) =
            *reinterpret_cast<const ushort8*>(&cst[r][c]);
    }
  }
}

// ======================= partition (self-scanned bases) =======================

__global__ __launch_bounds__(256) void partition_edges2(const int* __restrict__ src_all,
                                                        const int* __restrict__ dst_all,
                                                        const float* __restrict__ val_all,
                                                        const int* __restrict__ bucket_cnt,
                                                        int* __restrict__ cursor0,
                                                        int* __restrict__ bucket_base,
                                                        int2* __restrict__ part,
                                                        int TE, int n_nodes, int n_edges,
                                                        int NB) {
  __shared__ int cnt[256];
  __shared__ int base_s[256];
  __shared__ int tmp[256];
  const int tid = threadIdx.x;
  const int beg = blockIdx.x * EPB_P;
  const int end = min(beg + EPB_P, TE);

  int v = (tid < NB) ? bucket_cnt[tid] : 0;
  tmp[tid] = v;
  __syncthreads();
#pragma unroll
  for (int d = 1; d < 256; d <<= 1) {
    int t = (tid >= d) ? tmp[tid - d] : 0;
    __syncthreads();
    tmp[tid] += t;
    __syncthreads();
  }
  int excl = tmp[tid] - v;
  base_s[tid] = excl;
  if (blockIdx.x == 0) {
    if (tid < NB) bucket_base[tid] = excl;
    if (tid == 0) bucket_base[NB] = TE;
  }

  cnt[tid] = 0;
  __syncthreads();
  for (int i = beg + tid; i < end; i += 256) atomicAdd(&cnt[dst_all[i] >> 9], 1);
  __syncthreads();

  int c = cnt[tid];
  int mybase = (c > 0) ? base_s[tid] + atomicAdd(&cursor0[tid], c) : 0;
  __syncthreads();
  tmp[tid] = mybase;
  cnt[tid] = 0;
  __syncthreads();

  for (int i = beg + tid; i < end; i += 256) {
    int d = dst_all[i];
    int b = d >> 9;
    int r = atomicAdd(&cnt[b], 1);
    int s = i / n_edges;
    unsigned key = (unsigned)(s * n_nodes + src_all[i]) |
                   ((unsigned)(d & (BKT - 1)) << PACK_BITS);
    part[tmp[b] + r] = make_int2((int)key, __float_as_int(val_all[i]));
  }
}

// ======================= csr_build (per bucket) =======================

__global__ __launch_bounds__(256) void csr_build(const int2* __restrict__ part,
                                                 const int* __restrict__ bucket_base,
                                                 int2* __restrict__ csr,
                                                 int* __restrict__ row_off,
                                                 int n_nodes, int TE) {
  __shared__ int cnt[BKT];
  __shared__ int off_s[BKT];
  __shared__ int tmp[256];
  const int b = blockIdx.x;
  const int tid = threadIdx.x;
  const int bb = bucket_base[b];
  const int be = bucket_base[b + 1];

  cnt[tid] = 0;
  cnt[tid + 256] = 0;
  __syncthreads();
  for (int j = bb + tid; j < be; j += 256)
    atomicAdd(&cnt[((unsigned)part[j].x) >> PACK_BITS], 1);
  __syncthreads();

  int s2 = cnt[2 * tid] + cnt[2 * tid + 1];
  tmp[tid] = s2;
  __syncthreads();
#pragma unroll
  for (int d = 1; d < 256; d <<= 1) {
    int t = (tid >= d) ? tmp[tid - d] : 0;
    __syncthreads();
    tmp[tid] += t;
    __syncthreads();
  }
  int excl2 = tmp[tid] - s2;
  off_s[2 * tid] = excl2;
  off_s[2 * tid + 1] = excl2 + cnt[2 * tid];
  __syncthreads();

#pragma unroll
  for (int k = tid; k < BKT; k += 256) {
    int node = b * BKT + k;
    if (node < n_nodes) row_off[node] = bb + off_s[k];
  }
  cnt[tid] = off_s[tid];
  cnt[tid + 256] = off_s[tid + 256];
  __syncthreads();

  for (int j = bb + tid; j < be; j += 256) {
    int2 e = part[j];
    int dl = ((unsigned)e.x) >> PACK_BITS;
    int p = bb + atomicAdd(&cnt[dl], 1);
    csr[p] = e;
  }
  if (b == 0 && tid == 0) row_off[n_nodes] = TE;
}

// ======================= gather: 16 edges in flight per wave =======================
// 16 groups x 4 lanes; lane covers 64B (32 cols). Avg degree ~15 -> ONE latency
// round per node (was 2 with 8 groups).

__global__ __launch_bounds__(256) void spmm_gather16(const unsigned short* __restrict__ pre,
                                                     const int2* __restrict__ csr,
                                                     const int* __restrict__ row_off,
                                                     float* __restrict__ out, int n_nodes) {
  const int lane = threadIdx.x & 63;
  const int g = lane >> 2;       // edge group 0..15
  const int t = lane & 3;        // col chunk 0..3 (32 cols each)
  const int wave = blockIdx.x * (blockDim.x >> 6) + (threadIdx.x >> 6);
  const int nwaves = gridDim.x * (blockDim.x >> 6);

  for (int n = wave; n < n_nodes; n += nwaves) {
    const int beg = row_off[n];
    const int end = row_off[n + 1];
    float acc[32];
#pragma unroll
    for (int k = 0; k < 32; ++k) acc[k] = 0.f;

    for (int j = beg + g; j < end; j += 16) {
      const int2 e = csr[j];
      const float v = __int_as_float(e.y);
      const unsigned srcg = ((unsigned)e.x) & SRCG_MASK;
      const ushort8* pr =
          reinterpret_cast<const ushort8*>(&pre[(size_t)srcg * DOUT + t * 32]);
      ushort8 p0 = pr[0];
      ushort8 p1 = pr[1];
      ushort8 p2 = pr[2];
      ushort8 p3 = pr[3];
#pragma unroll
      for (int k = 0; k < 8; ++k) {
        acc[k]      = fmaf(v, __uint_as_float((unsigned int)(unsigned short)p0[k] << 16), acc[k]);
        acc[8 + k]  = fmaf(v, __uint_as_float((unsigned int)(unsigned short)p1[k] << 16), acc[8 + k]);
        acc[16 + k] = fmaf(v, __uint_as_float((unsigned int)(unsigned short)p2[k] << 16), acc[16 + k]);
        acc[24 + k] = fmaf(v, __uint_as_float((unsigned int)(unsigned short)p3[k] << 16), acc[24 + k]);
      }
    }

    // butterfly sum across the 16 groups (lane bits 2..5)
#pragma unroll
    for (int d = 4; d <= 32; d <<= 1)
#pragma unroll
      for (int k = 0; k < 32; ++k) acc[k] += __shfl_xor(acc[k], d, 64);

    // lane (g,t) writes cols t*32 + g*2, +1 — static select over g
    float r0 = 0.f, r1 = 0.f;
#pragma unroll
    for (int gg = 0; gg < 16; ++gg)
      if (gg == g) { r0 = acc[gg * 2]; r1 = acc[gg * 2 + 1]; }
    r0 = fmaxf(r0, 0.f);
    r1 = fmaxf(r1, 0.f);
    *reinterpret_cast<float2*>(&out[(size_t)n * DOUT + t * 32 + g * 2]) =
        make_float2(r0, r1);
  }
}

// ======================= tier-2/3 fallback kernels =======================

__global__ __launch_bounds__(256) void gemm_xw(const float* __restrict__ x,
                                               const float* __restrict__ W,
                                               float* __restrict__ pre,
                                               int n_nodes) {
  __shared__ float xsf[128][33];
  __shared__ float wtf[32][129];
  const float* Ws = W + (size_t)blockIdx.y * DIN * DOUT;
  float* pres = pre + (size_t)blockIdx.y * n_nodes * DOUT;
  const int tid = threadIdx.x;
  const int row0 = blockIdx.x * 128;
  const int tcol = tid & 15;
  const int trow = tid >> 4;
  float acc[8][8];
#pragma unroll
  for (int i = 0; i < 8; ++i)
#pragma unroll
    for (int j = 0; j < 8; ++j) acc[i][j] = 0.f;
#pragma unroll 1
  for (int kk = 0; kk < DIN; kk += 32) {
#pragma unroll
    for (int i = 0; i < 4; ++i) {
      int e = tid + i * 256;
      int r = e >> 3, c = (e & 7) * 4;
      int gr = row0 + r;
      float4 v = make_float4(0.f, 0.f, 0.f, 0.f);
      if (gr < n_nodes)
        v = *reinterpret_cast<const float4*>(&x[(size_t)gr * DIN + kk + c]);
      xsf[r][c] = v.x; xsf[r][c + 1] = v.y; xsf[r][c + 2] = v.z; xsf[r][c + 3] = v.w;
    }
#pragma unroll
    for (int i = 0; i < 4; ++i) {
      int e = tid + i * 256;
      int k = e >> 5, c = (e & 31) * 4;
      float4 v = *reinterpret_cast<const float4*>(&Ws[(size_t)(kk + k) * DOUT + c]);
      wtf[k][c] = v.x; wtf[k][c + 1] = v.y; wtf[k][c + 2] = v.z; wtf[k][c + 3] = v.w;
    }
    __syncthreads();
#pragma unroll 4
    for (int k = 0; k < 32; ++k) {
      float a[8], b[8];
#pragma unroll
      for (int i = 0; i < 8; ++i) a[i] = xsf[trow * 8 + i][k];
#pragma unroll
      for (int j = 0; j < 8; ++j) b[j] = wtf[k][tcol + 16 * j];
#pragma unroll
      for (int i = 0; i < 8; ++i)
#pragma unroll
        for (int j = 0; j < 8; ++j) acc[i][j] = fmaf(a[i], b[j], acc[i][j]);
    }
    __syncthreads();
  }
#pragma unroll
  for (int i = 0; i < 8; ++i) {
    int gr = row0 + trow * 8 + i;
    if (gr < n_nodes) {
#pragma unroll
      for (int j = 0; j < 8; ++j)
        pres[(size_t)gr * DOUT + tcol + 16 * j] = acc[i][j];
    }
  }
}

__global__ __launch_bounds__(256) void edge_hist(const int* __restrict__ dst_base,
                                                 int* __restrict__ counts,
                                                 int n_edges, int n_nodes) {
  int i = blockIdx.x * blockDim.x + threadIdx.x;
  int s = blockIdx.y;
  if (i < n_edges) atomicAdd(&counts[s * n_nodes + dst_base[(size_t)s * n_edges + i]], 1);
}

__global__ __launch_bounds__(256) void scan_local(const int* __restrict__ counts,
                                                  int* __restrict__ row_off,
                                                  int* __restrict__ partials, int n) {
  __shared__ int tmp[256];
  const int tid = threadIdx.x;
  const int base = blockIdx.x * 2048 + tid * 8;
  int v[8];
#pragma unroll
  for (int i = 0; i < 8; ++i) v[i] = (base + i < n) ? counts[base + i] : 0;
  int s = 0;
#pragma unroll
  for (int i = 0; i < 8; ++i) s += v[i];
  tmp[tid] = s;
  __syncthreads();
#pragma unroll
  for (int d = 1; d < 256; d <<= 1) {
    int t = (tid >= d) ? tmp[tid - d] : 0;
    __syncthreads();
    tmp[tid] += t;
    __syncthreads();
  }
  int p = tmp[tid] - s;
#pragma unroll
  for (int i = 0; i < 8; ++i) {
    if (base + i < n) row_off[base + i] = p;
    p += v[i];
  }
  if (tid == 255) partials[blockIdx.x] = tmp[255];
}

__global__ __launch_bounds__(256) void scan_partials_k(int* __restrict__ partials, int nblk) {
  __shared__ int tmp[256];
  const int tid = threadIdx.x;
  int v = (tid < nblk) ? partials[tid] : 0;
  tmp[tid] = v;
  __syncthreads();
#pragma unroll
  for (int d = 1; d < 256; d <<= 1) {
    int t = (tid >= d) ? tmp[tid - d] : 0;
    __syncthreads();
    tmp[tid] += t;
    __syncthreads();
  }
  if (tid < nblk) partials[tid] = tmp[tid] - v;
}

__global__ __launch_bounds__(256) void scan_finish(int* __restrict__ row_off,
                                                   int* __restrict__ cursor,
                                                   const int* __restrict__ partials,
                                                   int n, int total_edges) {
  const int off = partials[blockIdx.x];
  const int base = blockIdx.x * 2048 + threadIdx.x * 8;
#pragma unroll
  for (int i = 0; i < 8; ++i) {
    int idx = base + i;
    if (idx < n) {
      int v = row_off[idx] + off;
      row_off[idx] = v;
      cursor[idx] = v;
    }
  }
  if (blockIdx.x == 0 && threadIdx.x == 0) row_off[n] = total_edges;
}

__global__ __launch_bounds__(256) void edge_fill(const int* __restrict__ src_base,
                                                 const int* __restrict__ dst_base,
                                                 const float* __restrict__ val_base,
                                                 int* __restrict__ cursor,
                                                 int2* __restrict__ csr,
                                                 int n_edges, int n_nodes) {
  int i = blockIdx.x * blockDim.x + threadIdx.x;
  int s = blockIdx.y;
  if (i < n_edges) {
    size_t gi = (size_t)s * n_edges + i;
    int d = dst_base[gi];
    int pos = atomicAdd(&cursor[s * n_nodes + d], 1);
    csr[pos] = make_int2(src_base[gi], __float_as_int(val_base[gi]));
  }
}

__global__ __launch_bounds__(256) void spmm_gather(const float* __restrict__ pre,
                                                   const int2* __restrict__ csr,
                                                   const int* __restrict__ row_off,
                                                   float* __restrict__ out,
                                                   int n_nodes, int n_sup, int mode) {
  const int lane = threadIdx.x & 63;
  const int wave = blockIdx.x * (blockDim.x >> 6) + (threadIdx.x >> 6);
  const int nwaves = gridDim.x * (blockDim.x >> 6);
  for (int n = wave; n < n_nodes; n += nwaves) {
    float ax = 0.f, ay = 0.f;
    float2* o = reinterpret_cast<float2*>(&out[(size_t)n * DOUT + lane * 2]);
    if (mode & 1) { float2 prev = *o; ax = prev.x; ay = prev.y; }
    for (int s = 0; s < n_sup; ++s) {
      const float* ps = pre + (size_t)s * n_nodes * DOUT;
      const int row = s * n_nodes + n;
      const int beg = row_off[row];
      const int end = row_off[row + 1];
      for (int j = beg; j < end; ++j) {
        const int2 e = csr[j];
        const float v = __int_as_float(e.y);
        const float2 p = *reinterpret_cast<const float2*>(&ps[(size_t)e.x * DOUT + lane * 2]);
        ax = fmaf(v, p.x, ax);
        ay = fmaf(v, p.y, ay);
      }
    }
    if (mode & 2) { ax = fmaxf(ax, 0.f); ay = fmaxf(ay, 0.f); }
    *o = make_float2(ax, ay);
  }
}

__global__ __launch_bounds__(256) void zero_f4(float4* __restrict__ p, int n4) {
  int i = blockIdx.x * blockDim.x + threadIdx.x;
  int stride = gridDim.x * blockDim.x;
  float4 z = make_float4(0.f, 0.f, 0.f, 0.f);
  for (; i < n4; i += stride) p[i] = z;
}

__global__ __launch_bounds__(256) void relu_f4(float4* __restrict__ p, int n4) {
  int i = blockIdx.x * blockDim.x + threadIdx.x;
  int stride = gridDim.x * blockDim.x;
  for (; i < n4; i += stride) {
    float4 v = p[i];
    v.x = fmaxf(v.x, 0.f); v.y = fmaxf(v.y, 0.f);
    v.z = fmaxf(v.z, 0.f); v.w = fmaxf(v.w, 0.f);
    p[i] = v;
  }
}

__global__ __launch_bounds__(256) void spmm_atomic(const float* __restrict__ pre,
                                                   const int* __restrict__ src,
                                                   const int* __restrict__ dst,
                                                   const float* __restrict__ val,
                                                   float* __restrict__ out,
                                                   int n_edges) {
  const int lane = threadIdx.x & 63;
  const int wave = blockIdx.x * (blockDim.x >> 6) + (threadIdx.x >> 6);
  const int nwaves = gridDim.x * (blockDim.x >> 6);
  for (int e = wave; e < n_edges; e += nwaves) {
    int s = src[e];
    int d = dst[e];
    float v = val[e];
    const float2 p = *reinterpret_cast<const float2*>(&pre[(size_t)s * DOUT + lane * 2]);
    float* o = &out[(size_t)d * DOUT + lane * 2];
    atomicAdd(o, v * p.x);
    atomicAdd(o + 1, v * p.y);
  }
}

// ======================= host launch =======================

static inline size_t align_up(size_t v, size_t a) { return (v + a - 1) & ~(a - 1); }

extern "C" void kernel_launch(void* const* d_in, const int* in_sizes, int n_in,
                              void* d_out, int out_size, void* d_ws, size_t ws_size,
                              hipStream_t stream) {
  const float* x     = (const float*)d_in[0];
  const float* W     = (const float*)d_in[1];
  const int*   esrc  = (const int*)d_in[2];
  const int*   edst  = (const int*)d_in[3];
  const float* eval_ = (const float*)d_in[4];
  float* out = (float*)d_out;

  const int n_nodes    = in_sizes[0] / DIN;
  const int n_supports = in_sizes[1] / (DIN * DOUT);
  const int n_edges    = in_sizes[2] / n_supports;

  const int gemm_blocks = (n_nodes + 127) / 128;
  const int edge_blocks = (n_edges + 255) / 256;

  // -------- tier 1: fused [GEMM||count] + spread partition + csr_build + gather16 --------
  {
    const int NR = n_supports * n_nodes;
    const int TE = n_supports * n_edges;
    const int NB = (n_nodes + BKT - 1) / BKT;
    const int eb = (TE + EPB - 1) / EPB;
    const int eb_p = (TE + EPB_P - 1) / EPB_P;
    const int gather_blocks = (n_nodes + 3) / 4;
    char* w = (char*)d_ws;
    size_t off = 0;
    unsigned short* pre3 = (unsigned short*)(w + off); off += align_up((size_t)NR * DOUT * 2, 256);
    unsigned short* wT = (unsigned short*)(w + off);   off += align_up((size_t)n_supports * DIN * DOUT * 2, 256);
    int* row_off = (int*)(w + off);      off += align_up((size_t)(n_nodes + 1) * 4, 256);
    int2* part = (int2*)(w + off);       off += align_up((size_t)TE * 8, 256);
    int2* csr = (int2*)(w + off);        off += align_up((size_t)TE * 8, 256);
    int* bucket_cnt = (int*)(w + off);   off += align_up(256 * 4, 256);   // adjacent to cursor0
    int* cursor0 = (int*)(w + off);      off += align_up(256 * 4, 256);
    int* bucket_base = (int*)(w + off);  off += align_up(257 * 4, 256);

    const bool packable = (size_t)n_supports * n_nodes < (1u << PACK_BITS);

    if (off <= ws_size && NB <= 256 && packable) {
      wconvert<<<n_supports + 1, 256, 0, stream>>>(W, wT, bucket_cnt, n_supports);
      gemm_mfma_count<<<gemm_blocks + eb, 256, 0, stream>>>(
          x, wT, pre3, edst, bucket_cnt, n_nodes, n_supports, TE, gemm_blocks);
      partition_edges2<<<eb_p, 256, 0, stream>>>(esrc, edst, eval_, bucket_cnt, cursor0,
                                                 bucket_base, part, TE, n_nodes, n_edges, NB);
      csr_build<<<NB, 256, 0, stream>>>(part, bucket_base, csr, row_off, n_nodes, TE);
      spmm_gather16<<<gather_blocks, 256, 0, stream>>>(pre3, csr, row_off, out, n_nodes);
      return;
    }
  }

  // -------- tier 2: fp32 per-support CSR gather --------
  {
    const int scan_blocks = (n_nodes + 2047) / 2048;
    const int gather_blocks = (n_nodes + 3) / 4;
    char* w = (char*)d_ws;
    size_t off = 0;
    float* pre = (float*)(w + off);    off += align_up((size_t)n_nodes * DOUT * 4, 256);
    int* row_off = (int*)(w + off);    off += align_up((size_t)(n_nodes + 1) * 4, 256);
    int* cursor = (int*)(w + off);     off += align_up((size_t)n_nodes * 4, 256);
    int2* csr = (int2*)(w + off);      off += align_up((size_t)n_edges * 8, 256);
    int* partials = (int*)(w + off);   off += align_up(1024 * 4, 256);

    if (off <= ws_size && scan_blocks <= 256) {
      for (int s = 0; s < n_supports; ++s) {
        const int* src = esrc + (size_t)s * n_edges;
        const int* dst = edst + (size_t)s * n_edges;
        const float* val = eval_ + (size_t)s * n_edges;
        gemm_xw<<<dim3(gemm_blocks, 1), 256, 0, stream>>>(x, W + (size_t)s * DIN * DOUT,
                                                          pre, n_nodes);
        hipMemsetAsync(cursor, 0, (size_t)n_nodes * 4, stream);
        edge_hist<<<dim3(edge_blocks, 1), 256, 0, stream>>>(dst, cursor, n_edges, n_nodes);
        scan_local<<<scan_blocks, 256, 0, stream>>>(cursor, row_off, partials, n_nodes);
        scan_partials_k<<<1, 256, 0, stream>>>(partials, scan_blocks);
        scan_finish<<<scan_blocks, 256, 0, stream>>>(row_off, cursor, partials, n_nodes, n_edges);
        edge_fill<<<dim3(edge_blocks, 1), 256, 0, stream>>>(src, dst, val, cursor, csr,
                                                            n_edges, n_nodes);
        int mode = (s == 0) ? 0 : 1;
        if (s == n_supports - 1) mode |= 2;
        spmm_gather<<<gather_blocks, 256, 0, stream>>>(pre, csr, row_off, out,
                                                       n_nodes, 1, mode);
      }
      return;
    }
  }

  // -------- tier 3: atomic scatter --------
  {
    float* pre = (float*)d_ws;
    if (ws_size < (size_t)n_nodes * DOUT * 4) return;
    const int n4 = out_size / 4;
    zero_f4<<<2048, 256, 0, stream>>>((float4*)out, n4);
    for (int s = 0; s < n_supports; ++s) {
      gemm_xw<<<dim3(gemm_blocks, 1), 256, 0, stream>>>(x, W + (size_t)s * DIN * DOUT,
                                                        pre, n_nodes);
      spmm_atomic<<<2048, 256, 0, stream>>>(pre, esrc + (size_t)s * n_edges,
                                            edst + (size_t)s * n_edges,
                                            eval_ + (size_t)s * n_edges, out, n_edges);
    }
    relu_f4<<<2048, 256, 0, stream>>>((float4*)out, n4);
  }
}

// Round 15
// 178.177 us; speedup vs baseline: 1.3981x; 1.3981x over previous
//
#include <hip/hip_runtime.h>

#define DIN 128
#define DOUT 128
#define EPB 4096            // edges per block for fused count
#define EPB_P 2048          // edges per block for partition (more spread)
#define BKT 512             // nodes per bucket (dst >> 9)
#define PACK_BITS 19        // src_global bits; dst_low in bits 19..27
#define SRCG_MASK ((1u << PACK_BITS) - 1u)

typedef __attribute__((ext_vector_type(8))) short short8;
typedef __attribute__((ext_vector_type(4))) float f32x4;
typedef __attribute__((ext_vector_type(8))) unsigned short ushort8;

__device__ __forceinline__ unsigned short f2bf(float f) {
  unsigned int u = __float_as_uint(f);
  u += 0x7fffu + ((u >> 16) & 1u);   // round-to-nearest-even
  return (unsigned short)(u >> 16);
}

// ============ W -> W^T bf16 (blocks 0..S-1) + zero count buffers (block S) ============

__global__ __launch_bounds__(256) void wconvert(const float* __restrict__ W,
                                                unsigned short* __restrict__ wT,
                                                int* __restrict__ zbuf, int n_sup) {
  const int tid = threadIdx.x;
  if (blockIdx.x >= n_sup) {        // zero bucket_cnt + cursor0 (512 ints)
    zbuf[tid] = 0;
    zbuf[tid + 256] = 0;
    return;
  }
  __shared__ unsigned short buf[128][136];
  const int s = blockIdx.x;
  const float* Ws = W + (size_t)s * DIN * DOUT;
  unsigned short* wts = wT + (size_t)s * DIN * DOUT;
#pragma unroll
  for (int i = 0; i < 16; ++i) {
    int e = tid + i * 256;
    int k = e >> 5, c = (e & 31) * 4;
    float4 v = *reinterpret_cast<const float4*>(&Ws[(size_t)k * DOUT + c]);
    buf[c][k] = f2bf(v.x); buf[c + 1][k] = f2bf(v.y);
    buf[c + 2][k] = f2bf(v.z); buf[c + 3][k] = f2bf(v.w);
  }
  __syncthreads();
#pragma unroll
  for (int i = 0; i < 8; ++i) {
    int e = tid + i * 256;
    int r = e >> 4, c = (e & 15) * 8;
    *reinterpret_cast<ushort8*>(&wts[(size_t)r * DIN + c]) =
        *reinterpret_cast<const ushort8*>(&buf[r][c]);
  }
}

// ======================= fused MFMA GEMM + bucket_count (r13, best) =======================
// Swapped-operand MFMA, wave-private C-stage, no barriers in GEMM path.

__global__ __launch_bounds__(256) void gemm_mfma_count(const float* __restrict__ x,
                                                       const unsigned short* __restrict__ wT,
                                                       unsigned short* __restrict__ pre,
                                                       const int* __restrict__ dst_all,
                                                       int* __restrict__ bucket_cnt,
                                                       int n_nodes, int n_sup, int TE,
                                                       int gemm_blocks) {
  __shared__ unsigned short cst[128][136];

  const int tid = threadIdx.x;

  if (blockIdx.x >= gemm_blocks) {
    int* cnt = reinterpret_cast<int*>(&cst[0][0]);
    cnt[tid] = 0;
    __syncthreads();
    const int cb = blockIdx.x - gemm_blocks;
    const int beg = cb * EPB;
    const int end = min(beg + EPB, TE);
    for (int i = beg + tid; i < end; i += 256) atomicAdd(&cnt[dst_all[i] >> 9], 1);
    __syncthreads();
    int c = cnt[tid];
    if (c) atomicAdd(&bucket_cnt[tid], c);
    return;
  }

  const int lane = tid & 63;
  const int w = tid >> 6;
  const int row0 = blockIdx.x * 128;
  const int alr = lane & 15;
  const int akg = lane >> 4;

  short8 xfrag[4][2];
#pragma unroll
  for (int kc = 0; kc < 4; ++kc)
#pragma unroll
    for (int mt = 0; mt < 2; ++mt) {
      int gr = row0 + w * 32 + mt * 16 + alr;
      short8 a = {0, 0, 0, 0, 0, 0, 0, 0};
      if (gr < n_nodes) {
        const float4* p =
            reinterpret_cast<const float4*>(&x[(size_t)gr * DIN + kc * 32 + akg * 8]);
        float4 v0 = p[0];
        float4 v1 = p[1];
        a[0] = (short)f2bf(v0.x); a[1] = (short)f2bf(v0.y);
        a[2] = (short)f2bf(v0.z); a[3] = (short)f2bf(v0.w);
        a[4] = (short)f2bf(v1.x); a[5] = (short)f2bf(v1.y);
        a[6] = (short)f2bf(v1.z); a[7] = (short)f2bf(v1.w);
      }
      xfrag[kc][mt] = a;
    }

  for (int s = 0; s < n_sup; ++s) {
    const unsigned short* wts = wT + (size_t)s * DIN * DOUT;

    f32x4 acc[2][8];
#pragma unroll
    for (int mt = 0; mt < 2; ++mt)
#pragma unroll
      for (int nt = 0; nt < 8; ++nt) acc[mt][nt] = (f32x4){0.f, 0.f, 0.f, 0.f};

#pragma unroll
    for (int kc = 0; kc < 4; ++kc) {
      short8 wfrag[8];
#pragma unroll
      for (int nt = 0; nt < 8; ++nt)
        wfrag[nt] = *reinterpret_cast<const short8*>(
            &wts[(size_t)(nt * 16 + alr) * DIN + kc * 32 + akg * 8]);
#pragma unroll
      for (int mt = 0; mt < 2; ++mt)
#pragma unroll
        for (int nt = 0; nt < 8; ++nt)
          acc[mt][nt] = __builtin_amdgcn_mfma_f32_16x16x32_bf16(
              wfrag[nt], xfrag[kc][mt], acc[mt][nt], 0, 0, 0);
    }

    // swapped-D: lane holds node = mt*16+alr, out-cols nt*16 + akg*4..+3
#pragma unroll
    for (int mt = 0; mt < 2; ++mt)
#pragma unroll
      for (int nt = 0; nt < 8; ++nt) {
        unsigned u0 = (unsigned)f2bf(acc[mt][nt][0]) |
                      ((unsigned)f2bf(acc[mt][nt][1]) << 16);
        unsigned u1 = (unsigned)f2bf(acc[mt][nt][2]) |
                      ((unsigned)f2bf(acc[mt][nt][3]) << 16);
        *reinterpret_cast<uint2*>(&cst[w * 32 + mt * 16 + alr][nt * 16 + akg * 4]) =
            make_uint2(u0, u1);
      }
    // no __syncthreads: wave-private rows, wave-local store below

    unsigned short* ps = pre + (size_t)s * n_nodes * DOUT;
#pragma unroll
    for (int i = 0; i < 8; ++i) {
      int e = lane + i * 64;
      int r = w * 32 + (e >> 4);
      int c = (e & 15) * 8;
      int gr = row0 + r;
      if (gr < n_nodes)
        *reinterpret_cast<ushort8*>(&ps[(size_t)gr * DOUT + c]) =
            *reinterpret_cast<const ushort8*>(&cst[r][c]);
    }
  }
}

// ======================= partition (self-scanned bases) =======================

__global__ __launch_bounds__(256) void partition_edges2(const int* __restrict__ src_all,
                                                        const int* __restrict__ dst_all,
                                                        const float* __restrict__ val_all,
                                                        const int* __restrict__ bucket_cnt,
                                                        int* __restrict__ cursor0,
                                                        int* __restrict__ bucket_base,
                                                        int2* __restrict__ part,
                                                        int TE, int n_nodes, int n_edges,
                                                        int NB) {
  __shared__ int cnt[256];
  __shared__ int base_s[256];
  __shared__ int tmp[256];
  const int tid = threadIdx.x;
  const int beg = blockIdx.x * EPB_P;
  const int end = min(beg + EPB_P, TE);

  int v = (tid < NB) ? bucket_cnt[tid] : 0;
  tmp[tid] = v;
  __syncthreads();
#pragma unroll
  for (int d = 1; d < 256; d <<= 1) {
    int t = (tid >= d) ? tmp[tid - d] : 0;
    __syncthreads();
    tmp[tid] += t;
    __syncthreads();
  }
  int excl = tmp[tid] - v;
  base_s[tid] = excl;
  if (blockIdx.x == 0) {
    if (tid < NB) bucket_base[tid] = excl;
    if (tid == 0) bucket_base[NB] = TE;
  }

  cnt[tid] = 0;
  __syncthreads();
  for (int i = beg + tid; i < end; i += 256) atomicAdd(&cnt[dst_all[i] >> 9], 1);
  __syncthreads();

  int c = cnt[tid];
  int mybase = (c > 0) ? base_s[tid] + atomicAdd(&cursor0[tid], c) : 0;
  __syncthreads();
  tmp[tid] = mybase;
  cnt[tid] = 0;
  __syncthreads();

  for (int i = beg + tid; i < end; i += 256) {
    int d = dst_all[i];
    int b = d >> 9;
    int r = atomicAdd(&cnt[b], 1);
    int s = i / n_edges;
    unsigned key = (unsigned)(s * n_nodes + src_all[i]) |
                   ((unsigned)(d & (BKT - 1)) << PACK_BITS);
    part[tmp[b] + r] = make_int2((int)key, __float_as_int(val_all[i]));
  }
}

// ======================= csr_build (per bucket) =======================

__global__ __launch_bounds__(256) void csr_build(const int2* __restrict__ part,
                                                 const int* __restrict__ bucket_base,
                                                 int2* __restrict__ csr,
                                                 int* __restrict__ row_off,
                                                 int n_nodes, int TE) {
  __shared__ int cnt[BKT];
  __shared__ int off_s[BKT];
  __shared__ int tmp[256];
  const int b = blockIdx.x;
  const int tid = threadIdx.x;
  const int bb = bucket_base[b];
  const int be = bucket_base[b + 1];

  cnt[tid] = 0;
  cnt[tid + 256] = 0;
  __syncthreads();
  for (int j = bb + tid; j < be; j += 256)
    atomicAdd(&cnt[((unsigned)part[j].x) >> PACK_BITS], 1);
  __syncthreads();

  int s2 = cnt[2 * tid] + cnt[2 * tid + 1];
  tmp[tid] = s2;
  __syncthreads();
#pragma unroll
  for (int d = 1; d < 256; d <<= 1) {
    int t = (tid >= d) ? tmp[tid - d] : 0;
    __syncthreads();
    tmp[tid] += t;
    __syncthreads();
  }
  int excl2 = tmp[tid] - s2;
  off_s[2 * tid] = excl2;
  off_s[2 * tid + 1] = excl2 + cnt[2 * tid];
  __syncthreads();

#pragma unroll
  for (int k = tid; k < BKT; k += 256) {
    int node = b * BKT + k;
    if (node < n_nodes) row_off[node] = bb + off_s[k];
  }
  cnt[tid] = off_s[tid];
  cnt[tid + 256] = off_s[tid + 256];
  __syncthreads();

  for (int j = bb + tid; j < be; j += 256) {
    int2 e = part[j];
    int dl = ((unsigned)e.x) >> PACK_BITS;
    int p = bb + atomicAdd(&cnt[dl], 1);
    csr[p] = e;
  }
  if (b == 0 && tid == 0) row_off[n_nodes] = TE;
}

// ======================= gather: 8 edges in flight per wave (proven best) =======================

__global__ __launch_bounds__(256) void spmm_gather8(const unsigned short* __restrict__ pre,
                                                    const int2* __restrict__ csr,
                                                    const int* __restrict__ row_off,
                                                    float* __restrict__ out, int n_nodes) {
  const int lane = threadIdx.x & 63;
  const int g = lane >> 3;
  const int t = lane & 7;
  const int wave = blockIdx.x * (blockDim.x >> 6) + (threadIdx.x >> 6);
  const int nwaves = gridDim.x * (blockDim.x >> 6);

  for (int n = wave; n < n_nodes; n += nwaves) {
    const int beg = row_off[n];
    const int end = row_off[n + 1];
    float acc[16];
#pragma unroll
    for (int k = 0; k < 16; ++k) acc[k] = 0.f;

    for (int j = beg + g; j < end; j += 8) {
      const int2 e = csr[j];
      const float v = __int_as_float(e.y);
      const unsigned srcg = ((unsigned)e.x) & SRCG_MASK;
      const ushort8* pr =
          reinterpret_cast<const ushort8*>(&pre[(size_t)srcg * DOUT + t * 16]);
      ushort8 p0 = pr[0];
      ushort8 p1 = pr[1];
#pragma unroll
      for (int k = 0; k < 8; ++k) {
        acc[k]     = fmaf(v, __uint_as_float((unsigned int)(unsigned short)p0[k] << 16), acc[k]);
        acc[8 + k] = fmaf(v, __uint_as_float((unsigned int)(unsigned short)p1[k] << 16), acc[8 + k]);
      }
    }

#pragma unroll
    for (int d = 8; d <= 32; d <<= 1)
#pragma unroll
      for (int k = 0; k < 16; ++k) acc[k] += __shfl_xor(acc[k], d, 64);

    float r0 = 0.f, r1 = 0.f;
#pragma unroll
    for (int gg = 0; gg < 8; ++gg)
      if (gg == g) { r0 = acc[gg * 2]; r1 = acc[gg * 2 + 1]; }
    r0 = fmaxf(r0, 0.f);
    r1 = fmaxf(r1, 0.f);
    *reinterpret_cast<float2*>(&out[(size_t)n * DOUT + t * 16 + g * 2]) =
        make_float2(r0, r1);
  }
}

// ======================= tier-2/3 fallback kernels =======================

__global__ __launch_bounds__(256) void gemm_xw(const float* __restrict__ x,
                                               const float* __restrict__ W,
                                               float* __restrict__ pre,
                                               int n_nodes) {
  __shared__ float xsf[128][33];
  __shared__ float wtf[32][129];
  const float* Ws = W + (size_t)blockIdx.y * DIN * DOUT;
  float* pres = pre + (size_t)blockIdx.y * n_nodes * DOUT;
  const int tid = threadIdx.x;
  const int row0 = blockIdx.x * 128;
  const int tcol = tid & 15;
  const int trow = tid >> 4;
  float acc[8][8];
#pragma unroll
  for (int i = 0; i < 8; ++i)
#pragma unroll
    for (int j = 0; j < 8; ++j) acc[i][j] = 0.f;
#pragma unroll 1
  for (int kk = 0; kk < DIN; kk += 32) {
#pragma unroll
    for (int i = 0; i < 4; ++i) {
      int e = tid + i * 256;
      int r = e >> 3, c = (e & 7) * 4;
      int gr = row0 + r;
      float4 v = make_float4(0.f, 0.f, 0.f, 0.f);
      if (gr < n_nodes)
        v = *reinterpret_cast<const float4*>(&x[(size_t)gr * DIN + kk + c]);
      xsf[r][c] = v.x; xsf[r][c + 1] = v.y; xsf[r][c + 2] = v.z; xsf[r][c + 3] = v.w;
    }
#pragma unroll
    for (int i = 0; i < 4; ++i) {
      int e = tid + i * 256;
      int k = e >> 5, c = (e & 31) * 4;
      float4 v = *reinterpret_cast<const float4*>(&Ws[(size_t)(kk + k) * DOUT + c]);
      wtf[k][c] = v.x; wtf[k][c + 1] = v.y; wtf[k][c + 2] = v.z; wtf[k][c + 3] = v.w;
    }
    __syncthreads();
#pragma unroll 4
    for (int k = 0; k < 32; ++k) {
      float a[8], b[8];
#pragma unroll
      for (int i = 0; i < 8; ++i) a[i] = xsf[trow * 8 + i][k];
#pragma unroll
      for (int j = 0; j < 8; ++j) b[j] = wtf[k][tcol + 16 * j];
#pragma unroll
      for (int i = 0; i < 8; ++i)
#pragma unroll
        for (int j = 0; j < 8; ++j) acc[i][j] = fmaf(a[i], b[j], acc[i][j]);
    }
    __syncthreads();
  }
#pragma unroll
  for (int i = 0; i < 8; ++i) {
    int gr = row0 + trow * 8 + i;
    if (gr < n_nodes) {
#pragma unroll
      for (int j = 0; j < 8; ++j)
        pres[(size_t)gr * DOUT + tcol + 16 * j] = acc[i][j];
    }
  }
}

__global__ __launch_bounds__(256) void edge_hist(const int* __restrict__ dst_base,
                                                 int* __restrict__ counts,
                                                 int n_edges, int n_nodes) {
  int i = blockIdx.x * blockDim.x + threadIdx.x;
  int s = blockIdx.y;
  if (i < n_edges) atomicAdd(&counts[s * n_nodes + dst_base[(size_t)s * n_edges + i]], 1);
}

__global__ __launch_bounds__(256) void scan_local(const int* __restrict__ counts,
                                                  int* __restrict__ row_off,
                                                  int* __restrict__ partials, int n) {
  __shared__ int tmp[256];
  const int tid = threadIdx.x;
  const int base = blockIdx.x * 2048 + tid * 8;
  int v[8];
#pragma unroll
  for (int i = 0; i < 8; ++i) v[i] = (base + i < n) ? counts[base + i] : 0;
  int s = 0;
#pragma unroll
  for (int i = 0; i < 8; ++i) s += v[i];
  tmp[tid] = s;
  __syncthreads();
#pragma unroll
  for (int d = 1; d < 256; d <<= 1) {
    int t = (tid >= d) ? tmp[tid - d] : 0;
    __syncthreads();
    tmp[tid] += t;
    __syncthreads();
  }
  int p = tmp[tid] - s;
#pragma unroll
  for (int i = 0; i < 8; ++i) {
    if (base + i < n) row_off[base + i] = p;
    p += v[i];
  }
  if (tid == 255) partials[blockIdx.x] = tmp[255];
}

__global__ __launch_bounds__(256) void scan_partials_k(int* __restrict__ partials, int nblk) {
  __shared__ int tmp[256];
  const int tid = threadIdx.x;
  int v = (tid < nblk) ? partials[tid] : 0;
  tmp[tid] = v;
  __syncthreads();
#pragma unroll
  for (int d = 1; d < 256; d <<= 1) {
    int t = (tid >= d) ? tmp[tid - d] : 0;
    __syncthreads();
    tmp[tid] += t;
    __syncthreads();
  }
  if (tid < nblk) partials[tid] = tmp[tid] - v;
}

__global__ __launch_bounds__(256) void scan_finish(int* __restrict__ row_off,
                                                   int* __restrict__ cursor,
                                                   const int* __restrict__ partials,
                                                   int n, int total_edges) {
  const int off = partials[blockIdx.x];
  const int base = blockIdx.x * 2048 + threadIdx.x * 8;
#pragma unroll
  for (int i = 0; i < 8; ++i) {
    int idx = base + i;
    if (idx < n) {
      int v = row_off[idx] + off;
      row_off[idx] = v;
      cursor[idx] = v;
    }
  }
  if (blockIdx.x == 0 && threadIdx.x == 0) row_off[n] = total_edges;
}

__global__ __launch_bounds__(256) void edge_fill(const int* __restrict__ src_base,
                                                 const int* __restrict__ dst_base,
                                                 const float* __restrict__ val_base,
                                                 int* __restrict__ cursor,
                                                 int2* __restrict__ csr,
                                                 int n_edges, int n_nodes) {
  int i = blockIdx.x * blockDim.x + threadIdx.x;
  int s = blockIdx.y;
  if (i < n_edges) {
    size_t gi = (size_t)s * n_edges + i;
    int d = dst_base[gi];
    int pos = atomicAdd(&cursor[s * n_nodes + d], 1);
    csr[pos] = make_int2(src_base[gi], __float_as_int(val_base[gi]));
  }
}

__global__ __launch_bounds__(256) void spmm_gather(const float* __restrict__ pre,
                                                   const int2* __restrict__ csr,
                                                   const int* __restrict__ row_off,
                                                   float* __restrict__ out,
                                                   int n_nodes, int n_sup, int mode) {
  const int lane = threadIdx.x & 63;
  const int wave = blockIdx.x * (blockDim.x >> 6) + (threadIdx.x >> 6);
  const int nwaves = gridDim.x * (blockDim.x >> 6);
  for (int n = wave; n < n_nodes; n += nwaves) {
    float ax = 0.f, ay = 0.f;
    float2* o = reinterpret_cast<float2*>(&out[(size_t)n * DOUT + lane * 2]);
    if (mode & 1) { float2 prev = *o; ax = prev.x; ay = prev.y; }
    for (int s = 0; s < n_sup; ++s) {
      const float* ps = pre + (size_t)s * n_nodes * DOUT;
      const int row = s * n_nodes + n;
      const int beg = row_off[row];
      const int end = row_off[row + 1];
      for (int j = beg; j < end; ++j) {
        const int2 e = csr[j];
        const float v = __int_as_float(e.y);
        const float2 p = *reinterpret_cast<const float2*>(&ps[(size_t)e.x * DOUT + lane * 2]);
        ax = fmaf(v, p.x, ax);
        ay = fmaf(v, p.y, ay);
      }
    }
    if (mode & 2) { ax = fmaxf(ax, 0.f); ay = fmaxf(ay, 0.f); }
    *o = make_float2(ax, ay);
  }
}

__global__ __launch_bounds__(256) void zero_f4(float4* __restrict__ p, int n4) {
  int i = blockIdx.x * blockDim.x + threadIdx.x;
  int stride = gridDim.x * blockDim.x;
  float4 z = make_float4(0.f, 0.f, 0.f, 0.f);
  for (; i < n4; i += stride) p[i] = z;
}

__global__ __launch_bounds__(256) void relu_f4(float4* __restrict__ p, int n4) {
  int i = blockIdx.x * blockDim.x + threadIdx.x;
  int stride = gridDim.x * blockDim.x;
  for (; i < n4; i += stride) {
    float4 v = p[i];
    v.x = fmaxf(v.x, 0.f); v.y = fmaxf(v.y, 0.f);
    v.z = fmaxf(v.z, 0.f); v.w = fmaxf(v.w, 0.f);
    p[i] = v;
  }
}

__global__ __launch_bounds__(256) void spmm_atomic(const float* __restrict__ pre,
                                                   const int* __restrict__ src,
                                                   const int* __restrict__ dst,
                                                   const float* __restrict__ val,
                                                   float* __restrict__ out,
                                                   int n_edges) {
  const int lane = threadIdx.x & 63;
  const int wave = blockIdx.x * (blockDim.x >> 6) + (threadIdx.x >> 6);
  const int nwaves = gridDim.x * (blockDim.x >> 6);
  for (int e = wave; e < n_edges; e += nwaves) {
    int s = src[e];
    int d = dst[e];
    float v = val[e];
    const float2 p = *reinterpret_cast<const float2*>(&pre[(size_t)s * DOUT + lane * 2]);
    float* o = &out[(size_t)d * DOUT + lane * 2];
    atomicAdd(o, v * p.x);
    atomicAdd(o + 1, v * p.y);
  }
}

// ======================= host launch =======================

static inline size_t align_up(size_t v, size_t a) { return (v + a - 1) & ~(a - 1); }

extern "C" void kernel_launch(void* const* d_in, const int* in_sizes, int n_in,
                              void* d_out, int out_size, void* d_ws, size_t ws_size,
                              hipStream_t stream) {
  const float* x     = (const float*)d_in[0];
  const float* W     = (const float*)d_in[1];
  const int*   esrc  = (const int*)d_in[2];
  const int*   edst  = (const int*)d_in[3];
  const float* eval_ = (const float*)d_in[4];
  float* out = (float*)d_out;

  const int n_nodes    = in_sizes[0] / DIN;
  const int n_supports = in_sizes[1] / (DIN * DOUT);
  const int n_edges    = in_sizes[2] / n_supports;

  const int gemm_blocks = (n_nodes + 127) / 128;
  const int edge_blocks = (n_edges + 255) / 256;

  // -------- tier 1: fused [GEMM||count] + spread partition + csr_build + gather8 --------
  {
    const int NR = n_supports * n_nodes;
    const int TE = n_supports * n_edges;
    const int NB = (n_nodes + BKT - 1) / BKT;
    const int eb = (TE + EPB - 1) / EPB;
    const int eb_p = (TE + EPB_P - 1) / EPB_P;
    const int gather_blocks = (n_nodes + 3) / 4;
    char* w = (char*)d_ws;
    size_t off = 0;
    unsigned short* pre3 = (unsigned short*)(w + off); off += align_up((size_t)NR * DOUT * 2, 256);
    unsigned short* wT = (unsigned short*)(w + off);   off += align_up((size_t)n_supports * DIN * DOUT * 2, 256);
    int* row_off = (int*)(w + off);      off += align_up((size_t)(n_nodes + 1) * 4, 256);
    int2* part = (int2*)(w + off);       off += align_up((size_t)TE * 8, 256);
    int2* csr = (int2*)(w + off);        off += align_up((size_t)TE * 8, 256);
    int* bucket_cnt = (int*)(w + off);   off += align_up(256 * 4, 256);   // adjacent to cursor0
    int* cursor0 = (int*)(w + off);      off += align_up(256 * 4, 256);
    int* bucket_base = (int*)(w + off);  off += align_up(257 * 4, 256);

    const bool packable = (size_t)n_supports * n_nodes < (1u << PACK_BITS);

    if (off <= ws_size && NB <= 256 && packable) {
      wconvert<<<n_supports + 1, 256, 0, stream>>>(W, wT, bucket_cnt, n_supports);
      gemm_mfma_count<<<gemm_blocks + eb, 256, 0, stream>>>(
          x, wT, pre3, edst, bucket_cnt, n_nodes, n_supports, TE, gemm_blocks);
      partition_edges2<<<eb_p, 256, 0, stream>>>(esrc, edst, eval_, bucket_cnt, cursor0,
                                                 bucket_base, part, TE, n_nodes, n_edges, NB);
      csr_build<<<NB, 256, 0, stream>>>(part, bucket_base, csr, row_off, n_nodes, TE);
      spmm_gather8<<<gather_blocks, 256, 0, stream>>>(pre3, csr, row_off, out, n_nodes);
      return;
    }
  }

  // -------- tier 2: fp32 per-support CSR gather --------
  {
    const int scan_blocks = (n_nodes + 2047) / 2048;
    const int gather_blocks = (n_nodes + 3) / 4;
    char* w = (char*)d_ws;
    size_t off = 0;
    float* pre = (float*)(w + off);    off += align_up((size_t)n_nodes * DOUT * 4, 256);
    int* row_off = (int*)(w + off);    off += align_up((size_t)(n_nodes + 1) * 4, 256);
    int* cursor = (int*)(w + off);     off += align_up((size_t)n_nodes * 4, 256);
    int2* csr = (int2*)(w + off);      off += align_up((size_t)n_edges * 8, 256);
    int* partials = (int*)(w + off);   off += align_up(1024 * 4, 256);

    if (off <= ws_size && scan_blocks <= 256) {
      for (int s = 0; s < n_supports; ++s) {
        const int* src = esrc + (size_t)s * n_edges;
        const int* dst = edst + (size_t)s * n_edges;
        const float* val = eval_ + (size_t)s * n_edges;
        gemm_xw<<<dim3(gemm_blocks, 1), 256, 0, stream>>>(x, W + (size_t)s * DIN * DOUT,
                                                          pre, n_nodes);
        hipMemsetAsync(cursor, 0, (size_t)n_nodes * 4, stream);
        edge_hist<<<dim3(edge_blocks, 1), 256, 0, stream>>>(dst, cursor, n_edges, n_nodes);
        scan_local<<<scan_blocks, 256, 0, stream>>>(cursor, row_off, partials, n_nodes);
        scan_partials_k<<<1, 256, 0, stream>>>(partials, scan_blocks);
        scan_finish<<<scan_blocks, 256, 0, stream>>>(row_off, cursor, partials, n_nodes, n_edges);
        edge_fill<<<dim3(edge_blocks, 1), 256, 0, stream>>>(src, dst, val, cursor, csr,
                                                            n_edges, n_nodes);
        int mode = (s == 0) ? 0 : 1;
        if (s == n_supports - 1) mode |= 2;
        spmm_gather<<<gather_blocks, 256, 0, stream>>>(pre, csr, row_off, out,
                                                       n_nodes, 1, mode);
      }
      return;
    }
  }

  // -------- tier 3: atomic scatter --------
  {
    float* pre = (float*)d_ws;
    if (ws_size < (size_t)n_nodes * DOUT * 4) return;
    const int n4 = out_size / 4;
    zero_f4<<<2048, 256, 0, stream>>>((float4*)out, n4);
    for (int s = 0; s < n_supports; ++s) {
      gemm_xw<<<dim3(gemm_blocks, 1), 256, 0, stream>>>(x, W + (size_t)s * DIN * DOUT,
                                                        pre, n_nodes);
      spmm_atomic<<<2048, 256, 0, stream>>>(pre, esrc + (size_t)s * n_edges,
                                            edst + (size_t)s * n_edges,
                                            eval_ + (size_t)s * n_edges, out, n_edges);
    }
    relu_f4<<<2048, 256, 0, stream>>>((float4*)out, n4);
  }
}